// Round 6
// baseline (160.296 us; speedup 1.0000x reference)
//
#include <hip/hip_runtime.h>

// PopulationCoding, round 6.
//  Bench dur has ~65us fixed harness overhead; r5 compute = gemm 43 + epi 47.
//  K1: r2's double-buffer structure, de-risked: k-split grid gives 4 blk/CU
//      by count (TK=32 dbuf LDS = 33.3KB, exactly 4 fit), VGPR budget 128
//      (launch_bounds(256,4)) so prefetch regs fit without spill.
//      One barrier per chunk; prefetch loads issued before compute.
//  K2: FULL unroll of LIF + conv t-loops: shifts become immediates
//      (bfe+cvt = 2 insts/bit), rotation movs vanish. Target ~5.5k insts
//      vs r5's measured ~10.1k.
// B=1024, IN=512, D=256, P=8, T=32. Output [1024,256] fp32.

constexpr int IN_DIM  = 512;
constexpr int D_DIM   = 256;
constexpr int NTOT    = 2048;   // D*P
constexpr int T_STEPS = 32;

constexpr int TM = 64;
constexpr int TN = 64;
constexpr int TK = 32;
constexpr int KSPLIT = 256;            // K per z-slice (nsplit=2)
constexpr int NCH    = KSPLIT / TK;    // 8 chunks

// ---------------------------------------------------------------- K1: GEMM
__global__ __launch_bounds__(256, 4)
void popcode_gemm(const float* __restrict__ x,
                  const float* __restrict__ Wp,
                  float* __restrict__ ws)    // [2][1024][2048] partial I
{
    // As [buf][k][row] stride 66: row-pair b64 reads, banks (2k+2rg) 2-way
    // broadcast, conflict-free. Bs [buf][k][col] stride 64: b128 reads 2-way
    // aliased (free). Total 33.3 KB -> exactly 4 blocks/CU.
    __shared__ float As[2][TK][TM + 2];
    __shared__ float Bs[2][TK][TN];

    const int tid = threadIdx.x;
    const int b0  = blockIdx.x * TM;
    const int c0  = blockIdx.y * TN;
    const int k0  = blockIdx.z * KSPLIT;
    const int rg  = tid >> 3;      // 0..31
    const int dl  = tid & 7;       // 0..7
    const int r2  = rg * 2;

    float acc[2][8];
#pragma unroll
    for (int i = 0; i < 2; ++i)
#pragma unroll
        for (int j = 0; j < 8; ++j) acc[i][j] = 0.f;

    float4 ra[2], rb[2];

    auto load_regs = [&](int kc) {
#pragma unroll
        for (int i = 0; i < 2; ++i) {
            const int f = tid + 256 * i;                 // 0..511
            // A tile: 64 rows x 32 k -> row=f>>3, c4=(f&7)*4
            ra[i] = *reinterpret_cast<const float4*>(
                x + (b0 + (f >> 3)) * IN_DIM + kc + (f & 7) * 4);
            // B tile: 32 rows x 64 cols -> r=f>>4, c=(f&15)*4
            rb[i] = *reinterpret_cast<const float4*>(
                Wp + (kc + (f >> 4)) * NTOT + c0 + (f & 15) * 4);
        }
    };
    auto write_lds = [&](int buf) {
#pragma unroll
        for (int i = 0; i < 2; ++i) {
            const int f   = tid + 256 * i;
            const int row = f >> 3;
            const int c4  = (f & 7) * 4;
            As[buf][c4 + 0][row] = ra[i].x;
            As[buf][c4 + 1][row] = ra[i].y;
            As[buf][c4 + 2][row] = ra[i].z;
            As[buf][c4 + 3][row] = ra[i].w;
            *reinterpret_cast<float4*>(&Bs[buf][f >> 4][(f & 15) * 4]) = rb[i];
        }
    };

    load_regs(k0);
    write_lds(0);
    __syncthreads();

    for (int ch = 0; ch < NCH; ++ch) {
        const int cur = ch & 1;
        if (ch + 1 < NCH) load_regs(k0 + (ch + 1) * TK);   // in flight over compute

#pragma unroll
        for (int k = 0; k < TK; ++k) {
            const float2 a = *reinterpret_cast<const float2*>(&As[cur][k][r2]);
            const float4 u = *reinterpret_cast<const float4*>(&Bs[cur][k][dl * 8]);
            const float4 v = *reinterpret_cast<const float4*>(&Bs[cur][k][dl * 8 + 4]);
            acc[0][0] += a.x * u.x;  acc[0][1] += a.x * u.y;
            acc[0][2] += a.x * u.z;  acc[0][3] += a.x * u.w;
            acc[0][4] += a.x * v.x;  acc[0][5] += a.x * v.y;
            acc[0][6] += a.x * v.z;  acc[0][7] += a.x * v.w;
            acc[1][0] += a.y * u.x;  acc[1][1] += a.y * u.y;
            acc[1][2] += a.y * u.z;  acc[1][3] += a.y * u.w;
            acc[1][4] += a.y * v.x;  acc[1][5] += a.y * v.y;
            acc[1][6] += a.y * v.z;  acc[1][7] += a.y * v.w;
        }

        if (ch + 1 < NCH) {
            write_lds(cur ^ 1);   // other buffer: safe while peers read cur
            __syncthreads();      // one barrier per chunk
        }
    }

    float* dst = ws + (size_t)blockIdx.z * 1024 * NTOT;
#pragma unroll
    for (int bi = 0; bi < 2; ++bi) {
        float* p = dst + (size_t)(b0 + r2 + bi) * NTOT + c0 + dl * 8;
        *reinterpret_cast<float4*>(p)     = {acc[bi][0], acc[bi][1], acc[bi][2], acc[bi][3]};
        *reinterpret_cast<float4*>(p + 4) = {acc[bi][4], acc[bi][5], acc[bi][6], acc[bi][7]};
    }
}

// ------------------------------------------------------------ K2: epilogue
__global__ __launch_bounds__(256)
void popcode_epi(const float* __restrict__ ws,
                 const float* __restrict__ bp,
                 const float* __restrict__ thrs,
                 const float* __restrict__ rateW,
                 const float* __restrict__ rateB,
                 const float* __restrict__ c1w,
                 const float* __restrict__ c1b,
                 const float* __restrict__ c2w,
                 const float* __restrict__ c2b,
                 const float* __restrict__ fus,
                 float* __restrict__ out)
{
    const int g = blockIdx.x * 256 + threadIdx.x;   // 0..262143
    const int b = g >> 8;
    const int d = g & 255;

    // ---- uniform parameters: scalar loads -> SGPRs ----
    float thr[8], rw[8];
#pragma unroll
    for (int p = 0; p < 8; ++p) { thr[p] = thrs[p]; rw[p] = rateW[p]; }

    float w1[4][8][3], wb1[4], w2c[4];
#pragma unroll
    for (int c = 0; c < 4; ++c) {
        wb1[c] = c1b[c];
        w2c[c] = c2w[c];
#pragma unroll
        for (int p = 0; p < 8; ++p)
#pragma unroll
            for (int k = 0; k < 3; ++k)
                w1[c][p][k] = c1w[(c * 8 + p) * 3 + k];
    }
    const float rb_ = rateB[0];
    const float bb2 = c2b[0];
    const float f0 = fus[0], f1 = fus[1];
    const float fm = fmaxf(f0, f1);
    const float e0 = __expf(f0 - fm), e1 = __expf(f1 - fm);
    const float inv = 1.f / (e0 + e1);
    const float fw0 = e0 * inv, fw1 = e1 * inv;

    // ---- gather I for this (b,d): sum the two k-slices ----
    const size_t base  = (size_t)b * NTOT + d * 8;
    const size_t slice = (size_t)1024 * NTOT;
    const float4 l0 = *reinterpret_cast<const float4*>(ws + base);
    const float4 h0 = *reinterpret_cast<const float4*>(ws + base + 4);
    const float4 l1 = *reinterpret_cast<const float4*>(ws + slice + base);
    const float4 h1 = *reinterpret_cast<const float4*>(ws + slice + base + 4);
    float Iv[8] = {l0.x + l1.x, l0.y + l1.y, l0.z + l1.z, l0.w + l1.w,
                   h0.x + h1.x, h0.y + h1.y, h0.z + h1.z, h0.w + h1.w};

    float Imt[8], mem[8];
    unsigned swv[8];
    bool spk[8];
#pragma unroll
    for (int p = 0; p < 8; ++p) {
        Iv[p] += bp[d * 8 + p];
        Imt[p] = Iv[p] - thr[p];
        mem[p] = 0.f;
        swv[p] = 0u;
        spk[p] = false;
    }

    // LIF (FULL unroll: bit positions are immediates)
#pragma unroll
    for (int t = 0; t < T_STEPS; ++t) {
        const unsigned bit = 1u << t;
#pragma unroll
        for (int p = 0; p < 8; ++p) {
            mem[p] = 0.95f * mem[p] + (spk[p] ? Imt[p] : Iv[p]);
            spk[p] = mem[p] > thr[p];
            swv[p] |= spk[p] ? bit : 0u;
        }
    }

    // rate branch
    float rsum = 0.f;
#pragma unroll
    for (int p = 0; p < 8; ++p) rsum += (float)__popc(swv[p]) * rw[p];
    const float rdec = rsum * (1.f / 32.f) + rb_;

    // temporal branch (FULL unroll: shifts are immediates, rotation is
    // compile-time register renaming)
    float svp[8], svc[8], svn[8];
#pragma unroll
    for (int p = 0; p < 8; ++p) {
        svp[p] = 0.f;
        svc[p] = (float)(swv[p] & 1u);
    }
    float tacc = 0.f;
#pragma unroll
    for (int t = 0; t < T_STEPS; ++t) {
#pragma unroll
        for (int p = 0; p < 8; ++p)
            svn[p] = (t < 31) ? (float)((swv[p] >> (t + 1)) & 1u) : 0.f;
#pragma unroll
        for (int c = 0; c < 4; ++c) {
            float h = wb1[c];
#pragma unroll
            for (int p = 0; p < 8; ++p) {
                h = fmaf(w1[c][p][0], svp[p], h);
                h = fmaf(w1[c][p][1], svc[p], h);
                h = fmaf(w1[c][p][2], svn[p], h);
            }
            tacc = fmaf(fmaxf(h, 0.f), w2c[c], tacc);
        }
#pragma unroll
        for (int p = 0; p < 8; ++p) { svp[p] = svc[p]; svc[p] = svn[p]; }
    }
    const float temp = tacc * (1.f / 32.f) + bb2;

    out[b * D_DIM + d] = fw0 * rdec + fw1 * temp;
}

extern "C" void kernel_launch(void* const* d_in, const int* in_sizes, int n_in,
                              void* d_out, int out_size, void* d_ws, size_t ws_size,
                              hipStream_t stream) {
    const float* x     = (const float*)d_in[0];
    const float* Wp    = (const float*)d_in[1];
    const float* bp    = (const float*)d_in[2];
    const float* thrs  = (const float*)d_in[3];
    const float* rateW = (const float*)d_in[4];
    const float* rateB = (const float*)d_in[5];
    const float* c1w   = (const float*)d_in[6];
    const float* c1b   = (const float*)d_in[7];
    const float* c2w   = (const float*)d_in[8];
    const float* c2b   = (const float*)d_in[9];
    const float* fus   = (const float*)d_in[10];
    float* out = (float*)d_out;
    float* ws  = (float*)d_ws;

    dim3 g1(1024 / TM, NTOT / TN, 2);   // 16 x 32 x 2 = 1024 blocks (4/CU)
    popcode_gemm<<<g1, dim3(256), 0, stream>>>(x, Wp, ws);

    popcode_epi<<<dim3(1024), dim3(256), 0, stream>>>(
        ws, bp, thrs, rateW, rateB, c1w, c1b, c2w, c2b, fus, out);
}

// Round 8
// 158.976 us; speedup vs baseline: 1.0083x; 1.0083x over previous
//
#include <hip/hip_runtime.h>

// PopulationCoding, round 8 (= round-7 design + cvt_pkrtz type fix).
//  r6 decode: (a) launch_bounds(,4) re-capped VGPR to 64 -> dbuf spilled
//  (WRITE 31MB); (b) epi is operand-residency-bound: 96 fp32 conv weights
//  overflow the SGPR budget -> ~11k insts/thread vs ~5k essential.
//  K1: 4rx8c fragment (LDS bytes/FMA 156->94, pipe floor 33->20us),
//      128-thr blocks, TM=TN=64, TK=32 dbuf (33.8KB -> 4 blk/CU, 1024
//      blocks with ksplit=2), PLAIN launch_bounds(128) -> no spill.
//  K2: conv via v_dot2_f32_f16 (fdot2): spikes exact in fp16; weights
//      packed over p-pairs = 48 uniform half2 forced to SGPRs via
//      readfirstlane. 12 dot2 per (c,t) -> ~3.4k insts/thread.
//      LIF + rate branch stay exact fp32.
// B=1024, IN=512, D=256, P=8, T=32. Output [1024,256] fp32.

typedef _Float16 half2 __attribute__((ext_vector_type(2)));
typedef __fp16  fp16x2 __attribute__((ext_vector_type(2)));

static __device__ __forceinline__ half2 pk2(float a, float b) {
    return __builtin_bit_cast(half2, __builtin_amdgcn_cvt_pkrtz(a, b));
}

constexpr int IN_DIM  = 512;
constexpr int D_DIM   = 256;
constexpr int NTOT    = 2048;   // D*P
constexpr int T_STEPS = 32;

constexpr int TM = 64;
constexpr int TN = 64;
constexpr int TK = 32;
constexpr int KSPLIT = 256;            // K per z-slice (nsplit=2)
constexpr int NCH    = KSPLIT / TK;    // 8 chunks

// ---------------------------------------------------------------- K1: GEMM
__global__ __launch_bounds__(128)
void popcode_gemm(const float* __restrict__ x,
                  const float* __restrict__ Wp,
                  float* __restrict__ ws)    // [2][1024][2048] partial I
{
    // As [buf][k][row] stride 68 (68*4B = 272 = 16B-aligned per k-slice):
    //   4-row b128 read at banks 4*rg+{0..3}, rg in 0..15 -> 2-way
    //   aliasing (free), 8-way broadcast.
    // Bs [buf][k][col] stride 64: b128 reads 2-way aliased (free).
    // Total LDS 2*32*68*4 + 2*32*64*4 = 33.8 KB -> 4 blocks/CU.
    __shared__ float As[2][TK][TM + 4];
    __shared__ float Bs[2][TK][TN];

    const int tid = threadIdx.x;   // 0..127
    const int b0  = blockIdx.x * TM;
    const int c0  = blockIdx.y * TN;
    const int k0  = blockIdx.z * KSPLIT;
    const int rg  = tid >> 3;      // 0..15
    const int dl  = tid & 7;       // 0..7
    const int r4  = rg * 4;        // first of this thread's 4 rows

    float acc[4][8];
#pragma unroll
    for (int i = 0; i < 4; ++i)
#pragma unroll
        for (int j = 0; j < 8; ++j) acc[i][j] = 0.f;

    float4 ra[4], rb[4];

    auto load_regs = [&](int kc) {
#pragma unroll
        for (int i = 0; i < 4; ++i) {
            const int f = tid + 128 * i;                 // 0..511
            // A tile: 64 rows x 32 k -> row=f>>3, c4=(f&7)*4
            ra[i] = *reinterpret_cast<const float4*>(
                x + (b0 + (f >> 3)) * IN_DIM + kc + (f & 7) * 4);
            // B tile: 32 rows x 64 cols -> r=f>>4 (0..31), c=(f&15)*4
            rb[i] = *reinterpret_cast<const float4*>(
                Wp + (kc + (f >> 4)) * NTOT + c0 + (f & 15) * 4);
        }
    };
    auto write_lds = [&](int buf) {
#pragma unroll
        for (int i = 0; i < 4; ++i) {
            const int f   = tid + 128 * i;
            const int row = f >> 3;
            const int c4  = (f & 7) * 4;
            As[buf][c4 + 0][row] = ra[i].x;
            As[buf][c4 + 1][row] = ra[i].y;
            As[buf][c4 + 2][row] = ra[i].z;
            As[buf][c4 + 3][row] = ra[i].w;
            *reinterpret_cast<float4*>(&Bs[buf][f >> 4][(f & 15) * 4]) = rb[i];
        }
    };

    load_regs(k0);
    write_lds(0);
    __syncthreads();

    for (int ch = 0; ch < NCH; ++ch) {
        const int cur = ch & 1;
        if (ch + 1 < NCH) load_regs(k0 + (ch + 1) * TK);   // in flight over compute

#pragma unroll
        for (int k = 0; k < TK; ++k) {
            const float4 a = *reinterpret_cast<const float4*>(&As[cur][k][r4]);
            const float4 u = *reinterpret_cast<const float4*>(&Bs[cur][k][dl * 8]);
            const float4 v = *reinterpret_cast<const float4*>(&Bs[cur][k][dl * 8 + 4]);
            const float ar[4] = {a.x, a.y, a.z, a.w};
#pragma unroll
            for (int r = 0; r < 4; ++r) {
                acc[r][0] += ar[r] * u.x;  acc[r][1] += ar[r] * u.y;
                acc[r][2] += ar[r] * u.z;  acc[r][3] += ar[r] * u.w;
                acc[r][4] += ar[r] * v.x;  acc[r][5] += ar[r] * v.y;
                acc[r][6] += ar[r] * v.z;  acc[r][7] += ar[r] * v.w;
            }
        }

        if (ch + 1 < NCH) {
            write_lds(cur ^ 1);   // other buffer: safe while peers read cur
            __syncthreads();      // one barrier per chunk
        }
    }

    float* dst = ws + (size_t)blockIdx.z * 1024 * NTOT;
#pragma unroll
    for (int bi = 0; bi < 4; ++bi) {
        float* p = dst + (size_t)(b0 + r4 + bi) * NTOT + c0 + dl * 8;
        *reinterpret_cast<float4*>(p)     = {acc[bi][0], acc[bi][1], acc[bi][2], acc[bi][3]};
        *reinterpret_cast<float4*>(p + 4) = {acc[bi][4], acc[bi][5], acc[bi][6], acc[bi][7]};
    }
}

// ------------------------------------------------------------ K2: epilogue
__global__ __launch_bounds__(256)
void popcode_epi(const float* __restrict__ ws,
                 const float* __restrict__ bp,
                 const float* __restrict__ thrs,
                 const float* __restrict__ rateW,
                 const float* __restrict__ rateB,
                 const float* __restrict__ c1w,
                 const float* __restrict__ c1b,
                 const float* __restrict__ c2w,
                 const float* __restrict__ c2b,
                 const float* __restrict__ fus,
                 float* __restrict__ out)
{
    const int g = blockIdx.x * 256 + threadIdx.x;   // 0..262143
    const int b = g >> 8;
    const int d = g & 255;

    // ---- uniform parameters ----
    float thr[8], rw[8];
#pragma unroll
    for (int p = 0; p < 8; ++p) { thr[p] = thrs[p]; rw[p] = rateW[p]; }

    // conv1 weights packed over p-pairs as half2, forced into SGPRs:
    // w1p[c][k][j] = { w1[c][2j][k], w1[c][2j+1][k] }
    half2 w1p[4][3][4];
    float wb1[4], w2c[4];
#pragma unroll
    for (int c = 0; c < 4; ++c) {
        wb1[c] = c1b[c];
        w2c[c] = c2w[c];
#pragma unroll
        for (int k = 0; k < 3; ++k)
#pragma unroll
            for (int j = 0; j < 4; ++j) {
                const float wa = c1w[(c * 8 + 2 * j) * 3 + k];
                const float wb = c1w[(c * 8 + 2 * j + 1) * 3 + k];
                const half2 hv = {(_Float16)wa, (_Float16)wb};
                const unsigned u = __builtin_amdgcn_readfirstlane(
                    __builtin_bit_cast(unsigned, hv));
                w1p[c][k][j] = __builtin_bit_cast(half2, u);
            }
    }
    const float rb_ = rateB[0];
    const float bb2 = c2b[0];
    const float f0 = fus[0], f1 = fus[1];
    const float fm = fmaxf(f0, f1);
    const float e0 = __expf(f0 - fm), e1 = __expf(f1 - fm);
    const float inv = 1.f / (e0 + e1);
    const float fw0 = e0 * inv, fw1 = e1 * inv;

    // ---- gather I for this (b,d): sum the two k-slices ----
    const size_t base  = (size_t)b * NTOT + d * 8;
    const size_t slice = (size_t)1024 * NTOT;
    const float4 l0 = *reinterpret_cast<const float4*>(ws + base);
    const float4 h0 = *reinterpret_cast<const float4*>(ws + base + 4);
    const float4 l1 = *reinterpret_cast<const float4*>(ws + slice + base);
    const float4 h1 = *reinterpret_cast<const float4*>(ws + slice + base + 4);
    float Iv[8] = {l0.x + l1.x, l0.y + l1.y, l0.z + l1.z, l0.w + l1.w,
                   h0.x + h1.x, h0.y + h1.y, h0.z + h1.z, h0.w + h1.w};

    float Imt[8], mem[8];
    unsigned swv[8];
    bool spk[8];
#pragma unroll
    for (int p = 0; p < 8; ++p) {
        Iv[p] += bp[d * 8 + p];
        Imt[p] = Iv[p] - thr[p];
        mem[p] = 0.f;
        swv[p] = 0u;
        spk[p] = false;
    }

    // LIF (exact fp32): reset=spk_{t-1}; mem=beta*mem+I-reset*thr; spk=mem>thr
#pragma unroll
    for (int t = 0; t < T_STEPS; ++t) {
        const unsigned bit = 1u << t;
#pragma unroll
        for (int p = 0; p < 8; ++p) {
            mem[p] = 0.95f * mem[p] + (spk[p] ? Imt[p] : Iv[p]);
            spk[p] = mem[p] > thr[p];
            swv[p] |= spk[p] ? bit : 0u;
        }
    }

    // rate branch (exact fp32 via popcount)
    float rsum = 0.f;
#pragma unroll
    for (int p = 0; p < 8; ++p) rsum += (float)__popc(swv[p]) * rw[p];
    const float rdec = rsum * (1.f / 32.f) + rb_;

    // temporal branch: conv1 via fdot2 over p-pairs (spikes exact in fp16),
    // relu + conv2 + mean in fp32.
    half2 prevc[4], curc[4], nxtc[4];
#pragma unroll
    for (int j = 0; j < 4; ++j) {
        prevc[j] = half2{(_Float16)0.f, (_Float16)0.f};
        curc[j]  = pk2((float)(swv[2 * j] & 1u),
                       (float)(swv[2 * j + 1] & 1u));
    }
    float tacc = 0.f;
#pragma unroll
    for (int t = 0; t < T_STEPS; ++t) {
#pragma unroll
        for (int j = 0; j < 4; ++j) {
            if (t < 31)
                nxtc[j] = pk2((float)((swv[2 * j] >> (t + 1)) & 1u),
                              (float)((swv[2 * j + 1] >> (t + 1)) & 1u));
            else
                nxtc[j] = half2{(_Float16)0.f, (_Float16)0.f};
        }
#pragma unroll
        for (int c = 0; c < 4; ++c) {
            float h = wb1[c];
#pragma unroll
            for (int j = 0; j < 4; ++j)
                h = __builtin_amdgcn_fdot2(w1p[c][0][j], prevc[j], h, false);
#pragma unroll
            for (int j = 0; j < 4; ++j)
                h = __builtin_amdgcn_fdot2(w1p[c][1][j], curc[j], h, false);
#pragma unroll
            for (int j = 0; j < 4; ++j)
                h = __builtin_amdgcn_fdot2(w1p[c][2][j], nxtc[j], h, false);
            tacc = fmaf(fmaxf(h, 0.f), w2c[c], tacc);
        }
#pragma unroll
        for (int j = 0; j < 4; ++j) { prevc[j] = curc[j]; curc[j] = nxtc[j]; }
    }
    const float temp = tacc * (1.f / 32.f) + bb2;

    out[b * D_DIM + d] = fw0 * rdec + fw1 * temp;
}

extern "C" void kernel_launch(void* const* d_in, const int* in_sizes, int n_in,
                              void* d_out, int out_size, void* d_ws, size_t ws_size,
                              hipStream_t stream) {
    const float* x     = (const float*)d_in[0];
    const float* Wp    = (const float*)d_in[1];
    const float* bp    = (const float*)d_in[2];
    const float* thrs  = (const float*)d_in[3];
    const float* rateW = (const float*)d_in[4];
    const float* rateB = (const float*)d_in[5];
    const float* c1w   = (const float*)d_in[6];
    const float* c1b   = (const float*)d_in[7];
    const float* c2w   = (const float*)d_in[8];
    const float* c2b   = (const float*)d_in[9];
    const float* fus   = (const float*)d_in[10];
    float* out = (float*)d_out;
    float* ws  = (float*)d_ws;

    dim3 g1(1024 / TM, NTOT / TN, 2);   // 16 x 32 x 2 = 1024 blocks (4/CU)
    popcode_gemm<<<g1, dim3(128), 0, stream>>>(x, Wp, ws);

    popcode_epi<<<dim3(1024), dim3(256), 0, stream>>>(
        ws, bp, thrs, rateW, rateB, c1w, c1b, c2w, c2b, fus, out);
}

// Round 9
// 141.340 us; speedup vs baseline: 1.1341x; 1.1248x over previous
//
#include <hip/hip_runtime.h>

// PopulationCoding, round 9.
//  r8 decode: dbuf prefetch -> VGPR 236 -> 2 waves/SIMD -> gemm 60us.
//  Dropping double-buffering permanently (3 failures: spill/spill/VGPR).
//  K1 = r8's 4rx8c fragment, single-buffered: LDS bytes/FMA = 1.5
//      (4*(1/4+1/8)) -> ~31us LDS-return-pipe floor. 128 thr, TM=TN=64,
//      TK=64 (As 17.4K + Bs 16.4K = 33.8KB -> 4 blk/CU, 8 waves/CU),
//      ksplit=2, launch_bounds(128,2).
//  K2 = r8 epi untouched (proven 33us).
// B=1024, IN=512, D=256, P=8, T=32. Output [1024,256] fp32.

typedef _Float16 half2 __attribute__((ext_vector_type(2)));

static __device__ __forceinline__ half2 pk2(float a, float b) {
    return __builtin_bit_cast(half2, __builtin_amdgcn_cvt_pkrtz(a, b));
}

constexpr int IN_DIM  = 512;
constexpr int D_DIM   = 256;
constexpr int NTOT    = 2048;   // D*P
constexpr int T_STEPS = 32;

constexpr int TM = 64;
constexpr int TN = 64;
constexpr int TK = 64;
constexpr int KSPLIT = 256;            // K per z-slice (nsplit=2)

// ---------------------------------------------------------------- K1: GEMM
__global__ __launch_bounds__(128, 2)
void popcode_gemm(const float* __restrict__ x,
                  const float* __restrict__ Wp,
                  float* __restrict__ ws)    // [2][1024][2048] partial I
{
    // As [k][row] stride 68 (17.4 KB): 4-row b128 reads, 2-way aliased
    // (free), 8-way broadcast. Bs [k][col] stride 64 (16.4 KB): b128 reads
    // 2-way aliased (free). 33.8 KB total -> 4 blocks/CU.
    __shared__ float As[TK][TM + 4];
    __shared__ float Bs[TK][TN];

    const int tid = threadIdx.x;   // 0..127
    const int b0  = blockIdx.x * TM;
    const int c0  = blockIdx.y * TN;
    const int k0  = blockIdx.z * KSPLIT;
    const int rg  = tid >> 3;      // 0..15
    const int dl  = tid & 7;       // 0..7
    const int r4  = rg * 4;        // first of this thread's 4 rows

    float acc[4][8];
#pragma unroll
    for (int i = 0; i < 4; ++i)
#pragma unroll
        for (int j = 0; j < 8; ++j) acc[i][j] = 0.f;

    for (int kc = k0; kc < k0 + KSPLIT; kc += TK) {
        // stage A: 64x64, 128 thr x 8 float4; transpose into As
#pragma unroll
        for (int i = 0; i < 8; ++i) {
            const int f   = tid + 128 * i;       // 0..1023
            const int row = f >> 4;              // 0..63
            const int c4  = (f & 15) * 4;        // 0..60
            const float4 v =
                *reinterpret_cast<const float4*>(x + (b0 + row) * IN_DIM + kc + c4);
            As[c4 + 0][row] = v.x;
            As[c4 + 1][row] = v.y;
            As[c4 + 2][row] = v.z;
            As[c4 + 3][row] = v.w;
        }
        // stage B: 64x64, row-major b128 writes
#pragma unroll
        for (int i = 0; i < 8; ++i) {
            const int f  = tid + 128 * i;
            const int r  = f >> 4;
            const int c4 = (f & 15) * 4;
            *reinterpret_cast<float4*>(&Bs[r][c4]) =
                *reinterpret_cast<const float4*>(Wp + (kc + r) * NTOT + c0 + c4);
        }
        __syncthreads();

#pragma unroll 16
        for (int k = 0; k < TK; ++k) {
            const float4 a = *reinterpret_cast<const float4*>(&As[k][r4]);
            const float4 u = *reinterpret_cast<const float4*>(&Bs[k][dl * 8]);
            const float4 v = *reinterpret_cast<const float4*>(&Bs[k][dl * 8 + 4]);
            const float ar[4] = {a.x, a.y, a.z, a.w};
#pragma unroll
            for (int r = 0; r < 4; ++r) {
                acc[r][0] += ar[r] * u.x;  acc[r][1] += ar[r] * u.y;
                acc[r][2] += ar[r] * u.z;  acc[r][3] += ar[r] * u.w;
                acc[r][4] += ar[r] * v.x;  acc[r][5] += ar[r] * v.y;
                acc[r][6] += ar[r] * v.z;  acc[r][7] += ar[r] * v.w;
            }
        }
        __syncthreads();
    }

    float* dst = ws + (size_t)blockIdx.z * 1024 * NTOT;
#pragma unroll
    for (int bi = 0; bi < 4; ++bi) {
        float* p = dst + (size_t)(b0 + r4 + bi) * NTOT + c0 + dl * 8;
        *reinterpret_cast<float4*>(p)     = {acc[bi][0], acc[bi][1], acc[bi][2], acc[bi][3]};
        *reinterpret_cast<float4*>(p + 4) = {acc[bi][4], acc[bi][5], acc[bi][6], acc[bi][7]};
    }
}

// ------------------------------------------------------------ K2: epilogue
__global__ __launch_bounds__(256)
void popcode_epi(const float* __restrict__ ws,
                 const float* __restrict__ bp,
                 const float* __restrict__ thrs,
                 const float* __restrict__ rateW,
                 const float* __restrict__ rateB,
                 const float* __restrict__ c1w,
                 const float* __restrict__ c1b,
                 const float* __restrict__ c2w,
                 const float* __restrict__ c2b,
                 const float* __restrict__ fus,
                 float* __restrict__ out)
{
    const int g = blockIdx.x * 256 + threadIdx.x;   // 0..262143
    const int b = g >> 8;
    const int d = g & 255;

    // ---- uniform parameters ----
    float thr[8], rw[8];
#pragma unroll
    for (int p = 0; p < 8; ++p) { thr[p] = thrs[p]; rw[p] = rateW[p]; }

    // conv1 weights packed over p-pairs as half2, forced uniform:
    // w1p[c][k][j] = { w1[c][2j][k], w1[c][2j+1][k] }
    half2 w1p[4][3][4];
    float wb1[4], w2c[4];
#pragma unroll
    for (int c = 0; c < 4; ++c) {
        wb1[c] = c1b[c];
        w2c[c] = c2w[c];
#pragma unroll
        for (int k = 0; k < 3; ++k)
#pragma unroll
            for (int j = 0; j < 4; ++j) {
                const float wa = c1w[(c * 8 + 2 * j) * 3 + k];
                const float wb = c1w[(c * 8 + 2 * j + 1) * 3 + k];
                const half2 hv = {(_Float16)wa, (_Float16)wb};
                const unsigned u = __builtin_amdgcn_readfirstlane(
                    __builtin_bit_cast(unsigned, hv));
                w1p[c][k][j] = __builtin_bit_cast(half2, u);
            }
    }
    const float rb_ = rateB[0];
    const float bb2 = c2b[0];
    const float f0 = fus[0], f1 = fus[1];
    const float fm = fmaxf(f0, f1);
    const float e0 = __expf(f0 - fm), e1 = __expf(f1 - fm);
    const float inv = 1.f / (e0 + e1);
    const float fw0 = e0 * inv, fw1 = e1 * inv;

    // ---- gather I for this (b,d): sum the two k-slices ----
    const size_t base  = (size_t)b * NTOT + d * 8;
    const size_t slice = (size_t)1024 * NTOT;
    const float4 l0 = *reinterpret_cast<const float4*>(ws + base);
    const float4 h0 = *reinterpret_cast<const float4*>(ws + base + 4);
    const float4 l1 = *reinterpret_cast<const float4*>(ws + slice + base);
    const float4 h1 = *reinterpret_cast<const float4*>(ws + slice + base + 4);
    float Iv[8] = {l0.x + l1.x, l0.y + l1.y, l0.z + l1.z, l0.w + l1.w,
                   h0.x + h1.x, h0.y + h1.y, h0.z + h1.z, h0.w + h1.w};

    float Imt[8], mem[8];
    unsigned swv[8];
    bool spk[8];
#pragma unroll
    for (int p = 0; p < 8; ++p) {
        Iv[p] += bp[d * 8 + p];
        Imt[p] = Iv[p] - thr[p];
        mem[p] = 0.f;
        swv[p] = 0u;
        spk[p] = false;
    }

    // LIF (exact fp32): reset=spk_{t-1}; mem=beta*mem+I-reset*thr; spk=mem>thr
#pragma unroll
    for (int t = 0; t < T_STEPS; ++t) {
        const unsigned bit = 1u << t;
#pragma unroll
        for (int p = 0; p < 8; ++p) {
            mem[p] = 0.95f * mem[p] + (spk[p] ? Imt[p] : Iv[p]);
            spk[p] = mem[p] > thr[p];
            swv[p] |= spk[p] ? bit : 0u;
        }
    }

    // rate branch (exact fp32 via popcount)
    float rsum = 0.f;
#pragma unroll
    for (int p = 0; p < 8; ++p) rsum += (float)__popc(swv[p]) * rw[p];
    const float rdec = rsum * (1.f / 32.f) + rb_;

    // temporal branch: conv1 via fdot2 over p-pairs (spikes exact in fp16),
    // relu + conv2 + mean in fp32.
    half2 prevc[4], curc[4], nxtc[4];
#pragma unroll
    for (int j = 0; j < 4; ++j) {
        prevc[j] = half2{(_Float16)0.f, (_Float16)0.f};
        curc[j]  = pk2((float)(swv[2 * j] & 1u),
                       (float)(swv[2 * j + 1] & 1u));
    }
    float tacc = 0.f;
#pragma unroll
    for (int t = 0; t < T_STEPS; ++t) {
#pragma unroll
        for (int j = 0; j < 4; ++j) {
            if (t < 31)
                nxtc[j] = pk2((float)((swv[2 * j] >> (t + 1)) & 1u),
                              (float)((swv[2 * j + 1] >> (t + 1)) & 1u));
            else
                nxtc[j] = half2{(_Float16)0.f, (_Float16)0.f};
        }
#pragma unroll
        for (int c = 0; c < 4; ++c) {
            float h = wb1[c];
#pragma unroll
            for (int j = 0; j < 4; ++j)
                h = __builtin_amdgcn_fdot2(w1p[c][0][j], prevc[j], h, false);
#pragma unroll
            for (int j = 0; j < 4; ++j)
                h = __builtin_amdgcn_fdot2(w1p[c][1][j], curc[j], h, false);
#pragma unroll
            for (int j = 0; j < 4; ++j)
                h = __builtin_amdgcn_fdot2(w1p[c][2][j], nxtc[j], h, false);
            tacc = fmaf(fmaxf(h, 0.f), w2c[c], tacc);
        }
#pragma unroll
        for (int j = 0; j < 4; ++j) { prevc[j] = curc[j]; curc[j] = nxtc[j]; }
    }
    const float temp = tacc * (1.f / 32.f) + bb2;

    out[b * D_DIM + d] = fw0 * rdec + fw1 * temp;
}

extern "C" void kernel_launch(void* const* d_in, const int* in_sizes, int n_in,
                              void* d_out, int out_size, void* d_ws, size_t ws_size,
                              hipStream_t stream) {
    const float* x     = (const float*)d_in[0];
    const float* Wp    = (const float*)d_in[1];
    const float* bp    = (const float*)d_in[2];
    const float* thrs  = (const float*)d_in[3];
    const float* rateW = (const float*)d_in[4];
    const float* rateB = (const float*)d_in[5];
    const float* c1w   = (const float*)d_in[6];
    const float* c1b   = (const float*)d_in[7];
    const float* c2w   = (const float*)d_in[8];
    const float* c2b   = (const float*)d_in[9];
    const float* fus   = (const float*)d_in[10];
    float* out = (float*)d_out;
    float* ws  = (float*)d_ws;

    dim3 g1(1024 / TM, NTOT / TN, 2);   // 16 x 32 x 2 = 1024 blocks (4/CU)
    popcode_gemm<<<g1, dim3(128), 0, stream>>>(x, Wp, ws);

    popcode_epi<<<dim3(1024), dim3(256), 0, stream>>>(
        ws, bp, thrs, rateW, rateB, c1w, c1b, c2w, c2b, fus, out);
}

// Round 10
// 140.012 us; speedup vs baseline: 1.1449x; 1.0095x over previous
//
#include <hip/hip_runtime.h>

// PopulationCoding, round 10.
//  r9 decode: bench 141.3 = ~65 harness (268MB ws poison fill @42us + launch)
//             + gemm ~43 (LDS-return-bound, floor ~31) + epi ~33.
//  K1: UNCHANGED from r9 (proven; one variable per round).
//  K2: conv1 is linear in 24 spike bits = 3 bytes over p. Byte-LUT in LDS:
//      lut[k][byte][c] (12KB fp32) -> per t: 3 ds_read_b128 + ~20 VALU
//      replaces 48 fdot2. rate branch via rlut[byte] (1KB). LIF packs a
//      per-t spike byte into 8 u32s. Conv back to EXACT fp32.
// B=1024, IN=512, D=256, P=8, T=32. Output [1024,256] fp32.

constexpr int IN_DIM  = 512;
constexpr int D_DIM   = 256;
constexpr int NTOT    = 2048;   // D*P
constexpr int T_STEPS = 32;

constexpr int TM = 64;
constexpr int TN = 64;
constexpr int TK = 64;
constexpr int KSPLIT = 256;            // K per z-slice (nsplit=2)

// ---------------------------------------------------------------- K1: GEMM
__global__ __launch_bounds__(128, 2)
void popcode_gemm(const float* __restrict__ x,
                  const float* __restrict__ Wp,
                  float* __restrict__ ws)    // [2][1024][2048] partial I
{
    // As [k][row] stride 68 (17.4 KB): 4-row b128 reads, 2-way aliased
    // (free), 8-way broadcast. Bs [k][col] stride 64 (16.4 KB): b128 reads
    // 2-way aliased (free). 33.8 KB total -> 4 blocks/CU.
    __shared__ float As[TK][TM + 4];
    __shared__ float Bs[TK][TN];

    const int tid = threadIdx.x;   // 0..127
    const int b0  = blockIdx.x * TM;
    const int c0  = blockIdx.y * TN;
    const int k0  = blockIdx.z * KSPLIT;
    const int rg  = tid >> 3;      // 0..15
    const int dl  = tid & 7;       // 0..7
    const int r4  = rg * 4;        // first of this thread's 4 rows

    float acc[4][8];
#pragma unroll
    for (int i = 0; i < 4; ++i)
#pragma unroll
        for (int j = 0; j < 8; ++j) acc[i][j] = 0.f;

    for (int kc = k0; kc < k0 + KSPLIT; kc += TK) {
        // stage A: 64x64, 128 thr x 8 float4; transpose into As
#pragma unroll
        for (int i = 0; i < 8; ++i) {
            const int f   = tid + 128 * i;       // 0..1023
            const int row = f >> 4;              // 0..63
            const int c4  = (f & 15) * 4;        // 0..60
            const float4 v =
                *reinterpret_cast<const float4*>(x + (b0 + row) * IN_DIM + kc + c4);
            As[c4 + 0][row] = v.x;
            As[c4 + 1][row] = v.y;
            As[c4 + 2][row] = v.z;
            As[c4 + 3][row] = v.w;
        }
        // stage B: 64x64, row-major b128 writes
#pragma unroll
        for (int i = 0; i < 8; ++i) {
            const int f  = tid + 128 * i;
            const int r  = f >> 4;
            const int c4 = (f & 15) * 4;
            *reinterpret_cast<float4*>(&Bs[r][c4]) =
                *reinterpret_cast<const float4*>(Wp + (kc + r) * NTOT + c0 + c4);
        }
        __syncthreads();

#pragma unroll 16
        for (int k = 0; k < TK; ++k) {
            const float4 a = *reinterpret_cast<const float4*>(&As[k][r4]);
            const float4 u = *reinterpret_cast<const float4*>(&Bs[k][dl * 8]);
            const float4 v = *reinterpret_cast<const float4*>(&Bs[k][dl * 8 + 4]);
            const float ar[4] = {a.x, a.y, a.z, a.w};
#pragma unroll
            for (int r = 0; r < 4; ++r) {
                acc[r][0] += ar[r] * u.x;  acc[r][1] += ar[r] * u.y;
                acc[r][2] += ar[r] * u.z;  acc[r][3] += ar[r] * u.w;
                acc[r][4] += ar[r] * v.x;  acc[r][5] += ar[r] * v.y;
                acc[r][6] += ar[r] * v.z;  acc[r][7] += ar[r] * v.w;
            }
        }
        __syncthreads();
    }

    float* dst = ws + (size_t)blockIdx.z * 1024 * NTOT;
#pragma unroll
    for (int bi = 0; bi < 4; ++bi) {
        float* p = dst + (size_t)(b0 + r4 + bi) * NTOT + c0 + dl * 8;
        *reinterpret_cast<float4*>(p)     = {acc[bi][0], acc[bi][1], acc[bi][2], acc[bi][3]};
        *reinterpret_cast<float4*>(p + 4) = {acc[bi][4], acc[bi][5], acc[bi][6], acc[bi][7]};
    }
}

// ------------------------------------------------------------ K2: epilogue
__global__ __launch_bounds__(256)
void popcode_epi(const float* __restrict__ ws,
                 const float* __restrict__ bp,
                 const float* __restrict__ thrs,
                 const float* __restrict__ rateW,
                 const float* __restrict__ rateB,
                 const float* __restrict__ c1w,
                 const float* __restrict__ c1b,
                 const float* __restrict__ c2w,
                 const float* __restrict__ c2b,
                 const float* __restrict__ fus,
                 float* __restrict__ out)
{
    // lut[k][byte][c]: conv1 contribution of tap k for spike-byte `byte`,
    // channel c. 4 channels contiguous -> one ds_read_b128 per (k, byte).
    __shared__ float lut[3][256][4];     // 12 KB
    __shared__ float rlut[256];          // 1 KB: rate contribution per byte
    __shared__ float wlds[96];           // staged conv1 weights

    const int tid = threadIdx.x;
    const int g = blockIdx.x * 256 + tid;   // 0..262143
    const int b = g >> 8;
    const int d = g & 255;

    // ---- build LUTs (once per block) ----
    if (tid < 96) wlds[tid] = c1w[tid];
    {
        float rv = 0.f;
#pragma unroll
        for (int p = 0; p < 8; ++p)
            rv += (float)((tid >> p) & 1) * rateW[p];
        rlut[tid] = rv;
    }
    __syncthreads();
#pragma unroll
    for (int i = 0; i < 12; ++i) {
        const int e    = 256 * i + tid;      // 0..3071
        const int k    = e >> 10;
        const int byte = (e >> 2) & 255;
        const int c    = e & 3;
        float v = 0.f;
#pragma unroll
        for (int p = 0; p < 8; ++p)
            v = fmaf((float)((byte >> p) & 1), wlds[(c * 8 + p) * 3 + k], v);
        (&lut[0][0][0])[e] = v;
    }
    __syncthreads();

    // ---- uniform scalars ----
    float thr[8];
#pragma unroll
    for (int p = 0; p < 8; ++p) thr[p] = thrs[p];
    float wb1[4], w2c[4];
#pragma unroll
    for (int c = 0; c < 4; ++c) { wb1[c] = c1b[c]; w2c[c] = c2w[c]; }
    const float rb_ = rateB[0];
    const float bb2 = c2b[0];
    const float f0 = fus[0], f1 = fus[1];
    const float fm = fmaxf(f0, f1);
    const float e0 = __expf(f0 - fm), e1 = __expf(f1 - fm);
    const float inv = 1.f / (e0 + e1);
    const float fw0 = e0 * inv, fw1 = e1 * inv;

    // ---- gather I for this (b,d): sum the two k-slices ----
    const size_t base  = (size_t)b * NTOT + d * 8;
    const size_t slice = (size_t)1024 * NTOT;
    const float4 l0 = *reinterpret_cast<const float4*>(ws + base);
    const float4 h0 = *reinterpret_cast<const float4*>(ws + base + 4);
    const float4 l1 = *reinterpret_cast<const float4*>(ws + slice + base);
    const float4 h1 = *reinterpret_cast<const float4*>(ws + slice + base + 4);
    float Iv[8] = {l0.x + l1.x, l0.y + l1.y, l0.z + l1.z, l0.w + l1.w,
                   h0.x + h1.x, h0.y + h1.y, h0.z + h1.z, h0.w + h1.w};

    float Imt[8], mem[8];
    bool spk[8];
#pragma unroll
    for (int p = 0; p < 8; ++p) {
        Iv[p] += bp[d * 8 + p];
        Imt[p] = Iv[p] - thr[p];
        mem[p] = 0.f;
        spk[p] = false;
    }

    // LIF (exact fp32), emitting per-t spike bytes packed 4-per-u32.
    unsigned tb[8];
#pragma unroll
    for (int w = 0; w < 8; ++w) tb[w] = 0u;
#pragma unroll
    for (int t = 0; t < T_STEPS; ++t) {
        unsigned by = 0u;
#pragma unroll
        for (int p = 0; p < 8; ++p) {
            mem[p] = 0.95f * mem[p] + (spk[p] ? Imt[p] : Iv[p]);
            spk[p] = mem[p] > thr[p];
            by |= spk[p] ? (1u << p) : 0u;
        }
        tb[t >> 2] |= by << (8 * (t & 3));
    }

    // conv + rate in one t-loop. byte(t) = bfe(tb[t>>2], 8*(t&3), 8).
    const float* lutf = &lut[0][0][0];
    float tacc = 0.f, rsum = 0.f;
    unsigned bprev = 0u;
    unsigned bcur  = tb[0] & 255u;
#pragma unroll
    for (int t = 0; t < T_STEPS; ++t) {
        const unsigned bnext =
            (t < 31) ? ((tb[(t + 1) >> 2] >> (8 * ((t + 1) & 3))) & 255u) : 0u;
        const float4 fa = *reinterpret_cast<const float4*>(lutf + bprev * 4);
        const float4 fb = *reinterpret_cast<const float4*>(lutf + 1024 + bcur * 4);
        const float4 fc = *reinterpret_cast<const float4*>(lutf + 2048 + bnext * 4);
        rsum += rlut[bcur];
        const float h0_ = (fa.x + fb.x) + (fc.x + wb1[0]);
        const float h1_ = (fa.y + fb.y) + (fc.y + wb1[1]);
        const float h2_ = (fa.z + fb.z) + (fc.z + wb1[2]);
        const float h3_ = (fa.w + fb.w) + (fc.w + wb1[3]);
        tacc = fmaf(fmaxf(h0_, 0.f), w2c[0], tacc);
        tacc = fmaf(fmaxf(h1_, 0.f), w2c[1], tacc);
        tacc = fmaf(fmaxf(h2_, 0.f), w2c[2], tacc);
        tacc = fmaf(fmaxf(h3_, 0.f), w2c[3], tacc);
        bprev = bcur;
        bcur  = bnext;
    }
    const float rdec = rsum * (1.f / 32.f) + rb_;
    const float temp = tacc * (1.f / 32.f) + bb2;

    out[b * D_DIM + d] = fw0 * rdec + fw1 * temp;
}

extern "C" void kernel_launch(void* const* d_in, const int* in_sizes, int n_in,
                              void* d_out, int out_size, void* d_ws, size_t ws_size,
                              hipStream_t stream) {
    const float* x     = (const float*)d_in[0];
    const float* Wp    = (const float*)d_in[1];
    const float* bp    = (const float*)d_in[2];
    const float* thrs  = (const float*)d_in[3];
    const float* rateW = (const float*)d_in[4];
    const float* rateB = (const float*)d_in[5];
    const float* c1w   = (const float*)d_in[6];
    const float* c1b   = (const float*)d_in[7];
    const float* c2w   = (const float*)d_in[8];
    const float* c2b   = (const float*)d_in[9];
    const float* fus   = (const float*)d_in[10];
    float* out = (float*)d_out;
    float* ws  = (float*)d_ws;

    dim3 g1(1024 / TM, NTOT / TN, 2);   // 16 x 32 x 2 = 1024 blocks (4/CU)
    popcode_gemm<<<g1, dim3(128), 0, stream>>>(x, Wp, ws);

    popcode_epi<<<dim3(1024), dim3(256), 0, stream>>>(
        ws, bp, thrs, rateW, rateB, c1w, c1b, c2w, c2b, fus, out);
}

// Round 11
// 121.038 us; speedup vs baseline: 1.3243x; 1.1568x over previous
//
#include <hip/hip_runtime.h>
#include <type_traits>

// PopulationCoding, round 11.
//  r10 decode (with fill=42.8us constant): epi has been ~50us across THREE
//  different conv implementations -> bound by serial per-thread structure +
//  occupancy, not conv math. gemm ~44 vs ~34 LDS floor (8 waves/CU).
//  K1: TK=32 + ksplit=4 -> 2048 blocks, 8 blk/CU x 2 waves = 16 waves/CU.
//  K2: 2 threads/neuron, partner waves (h wave-uniform): each does LIF for
//      4 p's (independent chains), nibble exchange via LDS, each does half
//      the conv t-range. 2048 blocks, up to 32 waves/CU. LUT conv with
//      bias folded into tap 1. Exact fp32 throughout.
// B=1024, IN=512, D=256, P=8, T=32. Output [1024,256] fp32.

constexpr int IN_DIM  = 512;
constexpr int D_DIM   = 256;
constexpr int NTOT    = 2048;   // D*P
constexpr int T_STEPS = 32;

constexpr int TM = 64;
constexpr int TN = 64;
constexpr int TK = 32;
constexpr int NSPLIT = 4;
constexpr int KSPLIT = IN_DIM / NSPLIT;   // 128 -> 4 chunks of 32

// ---------------------------------------------------------------- K1: GEMM
__global__ __launch_bounds__(128, 2)
void popcode_gemm(const float* __restrict__ x,
                  const float* __restrict__ Wp,
                  float* __restrict__ ws)    // [4][1024][2048] partial I
{
    // As [k][row] stride 68: 4-row b128 reads, 2-way aliased (free),
    // 8-way broadcast. Bs [k][col] stride 64: b128 2-way aliased (free).
    // 16.5 KB total -> 8+ blocks/CU.
    __shared__ float As[TK][TM + 4];
    __shared__ float Bs[TK][TN];

    const int tid = threadIdx.x;   // 0..127
    const int b0  = blockIdx.x * TM;
    const int c0  = blockIdx.y * TN;
    const int k0  = blockIdx.z * KSPLIT;
    const int rg  = tid >> 3;      // 0..15
    const int dl  = tid & 7;       // 0..7
    const int r4  = rg * 4;        // first of this thread's 4 rows

    float acc[4][8];
#pragma unroll
    for (int i = 0; i < 4; ++i)
#pragma unroll
        for (int j = 0; j < 8; ++j) acc[i][j] = 0.f;

    for (int kc = k0; kc < k0 + KSPLIT; kc += TK) {
        // stage A: 64 rows x 32 k, 128 thr x 4 float4; transpose into As
#pragma unroll
        for (int i = 0; i < 4; ++i) {
            const int f   = tid + 128 * i;       // 0..511
            const int row = f >> 3;              // 0..63
            const int c4  = (f & 7) * 4;         // 0..28
            const float4 v =
                *reinterpret_cast<const float4*>(x + (b0 + row) * IN_DIM + kc + c4);
            As[c4 + 0][row] = v.x;
            As[c4 + 1][row] = v.y;
            As[c4 + 2][row] = v.z;
            As[c4 + 3][row] = v.w;
        }
        // stage B: 32 rows x 64 cols, row-major b128 writes
#pragma unroll
        for (int i = 0; i < 4; ++i) {
            const int f  = tid + 128 * i;        // 0..511
            const int r  = f >> 4;               // 0..31
            const int c4 = (f & 15) * 4;
            *reinterpret_cast<float4*>(&Bs[r][c4]) =
                *reinterpret_cast<const float4*>(Wp + (kc + r) * NTOT + c0 + c4);
        }
        __syncthreads();

#pragma unroll 16
        for (int k = 0; k < TK; ++k) {
            const float4 a = *reinterpret_cast<const float4*>(&As[k][r4]);
            const float4 u = *reinterpret_cast<const float4*>(&Bs[k][dl * 8]);
            const float4 v = *reinterpret_cast<const float4*>(&Bs[k][dl * 8 + 4]);
            const float ar[4] = {a.x, a.y, a.z, a.w};
#pragma unroll
            for (int r = 0; r < 4; ++r) {
                acc[r][0] += ar[r] * u.x;  acc[r][1] += ar[r] * u.y;
                acc[r][2] += ar[r] * u.z;  acc[r][3] += ar[r] * u.w;
                acc[r][4] += ar[r] * v.x;  acc[r][5] += ar[r] * v.y;
                acc[r][6] += ar[r] * v.z;  acc[r][7] += ar[r] * v.w;
            }
        }
        __syncthreads();
    }

    float* dst = ws + (size_t)blockIdx.z * 1024 * NTOT;
#pragma unroll
    for (int bi = 0; bi < 4; ++bi) {
        float* p = dst + (size_t)(b0 + r4 + bi) * NTOT + c0 + dl * 8;
        *reinterpret_cast<float4*>(p)     = {acc[bi][0], acc[bi][1], acc[bi][2], acc[bi][3]};
        *reinterpret_cast<float4*>(p + 4) = {acc[bi][4], acc[bi][5], acc[bi][6], acc[bi][7]};
    }
}

// ------------------------------------------------------------ K2: epilogue
// 2 threads per neuron: waves (0,1) and (2,3) are partner pairs (thread tid
// partners tid^64). h = wave&1 selects p-half (LIF) and t-half (conv).
__global__ __launch_bounds__(256)
void popcode_epi(const float* __restrict__ ws,
                 const float* __restrict__ bp,
                 const float* __restrict__ thrs,
                 const float* __restrict__ rateW,
                 const float* __restrict__ rateB,
                 const float* __restrict__ c1w,
                 const float* __restrict__ c1b,
                 const float* __restrict__ c2w,
                 const float* __restrict__ c2b,
                 const float* __restrict__ fus,
                 float* __restrict__ out)
{
    __shared__ float lut[3][256][4];     // 12 KB (bias folded into tap 1)
    __shared__ float rlut[256];          // 1 KB
    __shared__ float wlds[96];
    __shared__ uint4 exch[256];          // 4 KB nibble exchange / partial sums

    const int tid = threadIdx.x;
    const int wv  = tid >> 6;
    const int h   = wv & 1;                         // wave-uniform
    const int nl  = ((wv >> 1) << 6) | (tid & 63);  // 0..127
    const int n   = blockIdx.x * 128 + nl;
    const int b   = n >> 8;
    const int d   = n & 255;

    // ---- build LUTs (once per block) ----
    if (tid < 96) wlds[tid] = c1w[tid];
    {
        float rv = 0.f;
#pragma unroll
        for (int p = 0; p < 8; ++p)
            rv += (float)((tid >> p) & 1) * rateW[p];
        rlut[tid] = rv;
    }
    __syncthreads();
#pragma unroll
    for (int i = 0; i < 12; ++i) {
        const int e    = 256 * i + tid;      // 0..3071
        const int k    = e >> 10;
        const int byte = (e >> 2) & 255;
        const int c    = e & 3;
        float v = (k == 1) ? c1b[c] : 0.f;   // fold conv1 bias into tap 1
#pragma unroll
        for (int p = 0; p < 8; ++p)
            v = fmaf((float)((byte >> p) & 1), wlds[(c * 8 + p) * 3 + k], v);
        (&lut[0][0][0])[e] = v;
    }

    // ---- uniform scalars ----
    float w2c[4];
#pragma unroll
    for (int c = 0; c < 4; ++c) w2c[c] = c2w[c];
    const float rb_ = rateB[0];
    const float bb2 = c2b[0];
    const float f0 = fus[0], f1 = fus[1];
    const float fm = fmaxf(f0, f1);
    const float e0 = __expf(f0 - fm), e1 = __expf(f1 - fm);
    const float inv = 1.f / (e0 + e1);
    const float fw0 = e0 * inv, fw1 = e1 * inv;

    // ---- gather I for this thread's 4 p's: sum the 4 k-slices ----
    const size_t base  = (size_t)b * NTOT + d * 8 + h * 4;
    const size_t slice = (size_t)1024 * NTOT;
    float4 iv = *reinterpret_cast<const float4*>(ws + base);
#pragma unroll
    for (int s = 1; s < NSPLIT; ++s) {
        const float4 q = *reinterpret_cast<const float4*>(ws + s * slice + base);
        iv.x += q.x; iv.y += q.y; iv.z += q.z; iv.w += q.w;
    }
    const float4 bpv = *reinterpret_cast<const float4*>(bp + d * 8 + h * 4);
    const float4 tv  = *reinterpret_cast<const float4*>(thrs + h * 4);
    float Iv[4]  = {iv.x + bpv.x, iv.y + bpv.y, iv.z + bpv.z, iv.w + bpv.w};
    float thr[4] = {tv.x, tv.y, tv.z, tv.w};
    float Imt[4], mem[4];
    bool  spk[4];
#pragma unroll
    for (int p = 0; p < 4; ++p) {
        Imt[p] = Iv[p] - thr[p];
        mem[p] = 0.f;
        spk[p] = false;
    }

    // ---- LIF for 4 p's, packing a nibble per t (8 t per u32) ----
    unsigned nib[4] = {0u, 0u, 0u, 0u};
#pragma unroll
    for (int t = 0; t < T_STEPS; ++t) {
        unsigned nb = 0u;
#pragma unroll
        for (int p = 0; p < 4; ++p) {
            mem[p] = 0.95f * mem[p] + (spk[p] ? Imt[p] : Iv[p]);
            spk[p] = mem[p] > thr[p];
            nb |= spk[p] ? (1u << p) : 0u;
        }
        nib[t >> 3] |= nb << (4 * (t & 7));
    }

    // ---- exchange nibbles with the partner thread (other wave) ----
    __syncthreads();   // lut build + exch ready
    exch[tid] = uint4{nib[0], nib[1], nib[2], nib[3]};
    __syncthreads();
    const uint4 pr = exch[tid ^ 64];
    const unsigned prn[4] = {pr.x, pr.y, pr.z, pr.w};
    unsigned lo[4], hi[4];
#pragma unroll
    for (int w = 0; w < 4; ++w) {
        lo[w] = h ? prn[w] : nib[w];   // p0..3 half
        hi[w] = h ? nib[w] : prn[w];   // p4..7 half
    }

    // ---- conv + rate over this thread's half of the t-range ----
    auto getbyte = [&](int t) -> unsigned {
        const int w = t >> 3, s = 4 * (t & 7);
        return ((lo[w] >> s) & 15u) | (((hi[w] >> s) & 15u) << 4);
    };
    const float* lutf = &lut[0][0][0];
    float tacc = 0.f, rsum = 0.f;

    auto conv_half = [&](auto T0C) {
        constexpr int T0 = T0C.value;
        unsigned bprev = (T0 == 0) ? 0u : getbyte(T0 - 1);
        unsigned bcur  = getbyte(T0);
#pragma unroll
        for (int i = 0; i < 16; ++i) {
            const int t = T0 + i;
            const unsigned bnext = (t < 31) ? getbyte(t + 1) : 0u;
            const float4 fa = *reinterpret_cast<const float4*>(lutf + bprev * 4);
            const float4 fb = *reinterpret_cast<const float4*>(lutf + 1024 + bcur * 4);
            const float4 fc = *reinterpret_cast<const float4*>(lutf + 2048 + bnext * 4);
            rsum += rlut[bcur];
            const float h0_ = (fa.x + fb.x) + fc.x;
            const float h1_ = (fa.y + fb.y) + fc.y;
            const float h2_ = (fa.z + fb.z) + fc.z;
            const float h3_ = (fa.w + fb.w) + fc.w;
            tacc = fmaf(fmaxf(h0_, 0.f), w2c[0], tacc);
            tacc = fmaf(fmaxf(h1_, 0.f), w2c[1], tacc);
            tacc = fmaf(fmaxf(h2_, 0.f), w2c[2], tacc);
            tacc = fmaf(fmaxf(h3_, 0.f), w2c[3], tacc);
            bprev = bcur;
            bcur  = bnext;
        }
    };
    if (h == 0) conv_half(std::integral_constant<int, 0>{});
    else        conv_half(std::integral_constant<int, 16>{});

    // ---- combine partner partial sums, write ----
    __syncthreads();   // all exch reads done
    float2* e2 = reinterpret_cast<float2*>(exch);
    e2[tid] = float2{rsum, tacc};
    __syncthreads();
    const float2 q = e2[tid ^ 64];
    rsum += q.x;
    tacc += q.y;

    if (h == 0) {
        const float rdec = rsum * (1.f / 32.f) + rb_;
        const float temp = tacc * (1.f / 32.f) + bb2;
        out[b * D_DIM + d] = fw0 * rdec + fw1 * temp;
    }
}

extern "C" void kernel_launch(void* const* d_in, const int* in_sizes, int n_in,
                              void* d_out, int out_size, void* d_ws, size_t ws_size,
                              hipStream_t stream) {
    const float* x     = (const float*)d_in[0];
    const float* Wp    = (const float*)d_in[1];
    const float* bp    = (const float*)d_in[2];
    const float* thrs  = (const float*)d_in[3];
    const float* rateW = (const float*)d_in[4];
    const float* rateB = (const float*)d_in[5];
    const float* c1w   = (const float*)d_in[6];
    const float* c1b   = (const float*)d_in[7];
    const float* c2w   = (const float*)d_in[8];
    const float* c2b   = (const float*)d_in[9];
    const float* fus   = (const float*)d_in[10];
    float* out = (float*)d_out;
    float* ws  = (float*)d_ws;

    dim3 g1(1024 / TM, NTOT / TN, NSPLIT);   // 16 x 32 x 4 = 2048 blocks
    popcode_gemm<<<g1, dim3(128), 0, stream>>>(x, Wp, ws);

    popcode_epi<<<dim3(2048), dim3(256), 0, stream>>>(
        ws, bp, thrs, rateW, rateB, c1w, c1b, c2w, c2b, fus, out);
}